// Round 4
// baseline (39.060 us; speedup 1.0000x reference)
//
#include <hip/hip_runtime.h>

#define PAD 2
#define PX 4                 // pixels per thread along x
#define PY 2                 // pixels per thread along y
#define BDX 16
#define BDY 16
#define TSX (BDX * PX)       // 64 outputs wide per block
#define TSY (BDY * PY)       // 32 outputs high per block

// 16B vector with only 4B alignment guarantee -> global_load_dwordx4 (legal at dword alignment)
typedef float float4u __attribute__((vector_size(16), aligned(4)));

// compare-exchange: a <- min, b <- max  (dead outputs are DCE'd by the compiler)
#define CE(a, b) { float _lo = fminf(a, b), _hi = fmaxf(a, b); (a) = _lo; (b) = _hi; }

// full sort of 5 (Knuth optimal 9-CE network)
#define SORT5(t0, t1, t2, t3, t4) \
    CE(t0, t1) CE(t3, t4) CE(t2, t4) CE(t2, t3) CE(t0, t3) \
    CE(t0, t2) CE(t1, t4) CE(t1, t3) CE(t1, t2)

// full sort of 4 (5-CE network)
#define SORT4(t0, t1, t2, t3) \
    CE(t0, t1) CE(t2, t3) CE(t0, t2) CE(t1, t3) CE(t1, t2)

// insert e into sorted (s1<=s2<=s3<=s4) -> o0..o4 sorted ascending (bubble insertion, 8 ops)
#define INSERT5(o0, o1, o2, o3, o4, s1, s2, s3, s4, e) { \
    float _t  = fminf(s4, e);   o4 = fmaxf(s4, e); \
    float _t2 = fminf(s3, _t);  o3 = fmaxf(s3, _t); \
    float _t3 = fminf(s2, _t2); o2 = fmaxf(s2, _t2); \
    o0 = fminf(s1, _t3);        o1 = fmaxf(s1, _t3); }

// place max at t4, 2nd-largest at t3 (exact order statistics)
#define TOP2(t0, t1, t2, t3, t4) \
    CE(t0, t1) CE(t2, t3) CE(t1, t3) CE(t3, t4) \
    CE(t0, t1) CE(t2, t3) CE(t1, t3)

// place min at t0, 2nd-smallest at t1 (exact order statistics)
#define BOT2(t0, t1, t2, t3, t4) \
    CE(t0, t1) CE(t2, t3) CE(t0, t2) CE(t0, t4) \
    CE(t1, t2) CE(t3, t4) CE(t1, t3)

// median of 9 in q4 (Devillard 19-CE network)
#define MED9(q0, q1, q2, q3, q4, q5, q6, q7, q8) \
    CE(q1, q2) CE(q4, q5) CE(q7, q8) \
    CE(q0, q1) CE(q3, q4) CE(q6, q7) \
    CE(q1, q2) CE(q4, q5) CE(q7, q8) \
    CE(q0, q3) CE(q5, q8) CE(q4, q7) \
    CE(q3, q6) CE(q1, q4) CE(q2, q5) \
    CE(q4, q7) CE(q4, q2) CE(q6, q4) \
    CE(q4, q2)

__global__ __launch_bounds__(256) void denoise_median5_kernel(
    const float* __restrict__ x,
    const float* __restrict__ noise_var_p,
    const float* __restrict__ noise_bias_p,
    float* __restrict__ out,
    int H, int W)
{
    const float noise_var  = noise_var_p[0];
    const float noise_bias = noise_bias_p[0];

    const int b      = blockIdx.z;
    const int tile_y = blockIdx.y * TSY;
    const int tile_x = blockIdx.x * TSX;
    const int tx = threadIdx.x;
    const int ty = threadIdx.y;

    const float* __restrict__ img = x + (size_t)b * H * W;

    const int oy0 = tile_y + ty * PY;        // first of the two output rows
    const int gx0 = tile_x + tx * PX - PAD;  // leftmost input column

    // c[k][r]: column k (of 8), input row r (of 6, rows oy0-2 .. oy0+3)
    float c[8][6];

    const bool interior = (blockIdx.x > 0) && (blockIdx.x < gridDim.x - 1) &&
                          (blockIdx.y > 0) && (blockIdx.y < gridDim.y - 1);
    if (interior) {
        // no bounds logic at all; misaligned (8B) dwordx4 loads are legal
        const float* base = img + (size_t)(oy0 - PAD) * W + gx0;
        #pragma unroll
        for (int r = 0; r < 6; ++r) {
            const float* p = base + (size_t)r * W;
            float4u a = *(const float4u*)(p);
            float4u d = *(const float4u*)(p + 4);
            c[0][r] = a[0]; c[1][r] = a[1]; c[2][r] = a[2]; c[3][r] = a[3];
            c[4][r] = d[0]; c[5][r] = d[1]; c[6][r] = d[2]; c[7][r] = d[3];
        }
    } else {
        #pragma unroll
        for (int r = 0; r < 6; ++r) {
            const int gy = oy0 - PAD + r;
            const bool oky = ((unsigned)gy < (unsigned)H);
            #pragma unroll
            for (int k = 0; k < 8; ++k) {
                const int gx = gx0 + k;
                const bool ok = oky && ((unsigned)gx < (unsigned)W);
                c[k][r] = ok ? img[(size_t)gy * W + gx] : 0.0f;
            }
        }
    }

    // Center pixel values (raw, before sorting).
    float centerA[PX], centerB[PX];
    #pragma unroll
    for (int p = 0; p < PX; ++p) { centerA[p] = c[p + 2][2]; centerB[p] = c[p + 2][3]; }

    // Per-column sums / sums-of-squares, shared rows 1..4 between the two windows.
    float sum5A[PX], sq5A[PX], sum5B[PX], sq5B[PX];
    {
        float sA8[8], qA8[8], sB8[8], qB8[8];
        #pragma unroll
        for (int k = 0; k < 8; ++k) {
            const float sh = (c[k][1] + c[k][2]) + (c[k][3] + c[k][4]);
            float qh = c[k][1] * c[k][1];
            qh = fmaf(c[k][2], c[k][2], qh);
            qh = fmaf(c[k][3], c[k][3], qh);
            qh = fmaf(c[k][4], c[k][4], qh);
            sA8[k] = sh + c[k][0];  qA8[k] = fmaf(c[k][0], c[k][0], qh);
            sB8[k] = sh + c[k][5];  qB8[k] = fmaf(c[k][5], c[k][5], qh);
        }
        sum5A[0] = ((sA8[0] + sA8[1]) + (sA8[2] + sA8[3])) + sA8[4];
        sq5A[0]  = ((qA8[0] + qA8[1]) + (qA8[2] + qA8[3])) + qA8[4];
        sum5B[0] = ((sB8[0] + sB8[1]) + (sB8[2] + sB8[3])) + sB8[4];
        sq5B[0]  = ((qB8[0] + qB8[1]) + (qB8[2] + qB8[3])) + qB8[4];
        #pragma unroll
        for (int p = 1; p < PX; ++p) {
            sum5A[p] = sum5A[p - 1] - sA8[p - 1] + sA8[p + 4];
            sq5A[p]  = sq5A[p - 1]  - qA8[p - 1] + qA8[p + 4];
            sum5B[p] = sum5B[p - 1] - sB8[p - 1] + sB8[p + 4];
            sq5B[p]  = sq5B[p - 1]  - qB8[p - 1] + qB8[p + 4];
        }
    }

    // Shared sort of rows 1..4 per column (in place).
    #pragma unroll
    for (int k = 0; k < 8; ++k) {
        SORT4(c[k][1], c[k][2], c[k][3], c[k][4]);
    }

    float* outp = out + (size_t)b * H * W;

    // Process one window (given its 8 sorted 5-columns) -> 4 outputs
    auto run_window = [&](const float (&col)[8][5], const float (&center)[PX],
                          const float (&sum5)[PX], const float (&sq5)[PX]) -> float4u {
        float4u res;
        #pragma unroll
        for (int p = 0; p < PX; ++p) {
            float A1, A2;            // row0 sorted pos 3,4
            {
                float t0 = col[p][0], t1 = col[p+1][0], t2 = col[p+2][0], t3 = col[p+3][0], t4 = col[p+4][0];
                TOP2(t0, t1, t2, t3, t4);
                A1 = t3; A2 = t4;
            }
            float B1, B2, B3;        // row1 sorted pos 2,3,4
            {
                float t0 = col[p][1], t1 = col[p+1][1], t2 = col[p+2][1], t3 = col[p+3][1], t4 = col[p+4][1];
                SORT5(t0, t1, t2, t3, t4);
                B1 = t2; B2 = t3; B3 = t4;
            }
            float C1, C2, C3;        // row2 sorted pos 1,2,3
            {
                float t0 = col[p][2], t1 = col[p+1][2], t2 = col[p+2][2], t3 = col[p+3][2], t4 = col[p+4][2];
                SORT5(t0, t1, t2, t3, t4);
                C1 = t1; C2 = t2; C3 = t3;
            }
            float D1, D2, D3;        // row3 sorted pos 0,1,2
            {
                float t0 = col[p][3], t1 = col[p+1][3], t2 = col[p+2][3], t3 = col[p+3][3], t4 = col[p+4][3];
                SORT5(t0, t1, t2, t3, t4);
                D1 = t0; D2 = t1; D3 = t2;
            }
            float E1, E2;            // row4 sorted pos 0,1
            {
                float t0 = col[p][4], t1 = col[p+1][4], t2 = col[p+2][4], t3 = col[p+3][4], t4 = col[p+4][4];
                BOT2(t0, t1, t2, t3, t4);
                E1 = t0; E2 = t1;
            }

            // poset elimination: 13 candidates -> 9 (rank-counted, provably safe)
            const float mn1 = fminf(B3, D3);
            const float mn2 = fminf(C3, E2);
            const float mx1 = fmaxf(B1, D1);
            const float mx2 = fmaxf(A1, C1);

            float q0 = mx2, q1 = A2, q2 = B2, q3 = C2, q4 = D2,
                  q5 = E1, q6 = mx1, q7 = mn1, q8 = mn2;
            MED9(q0, q1, q2, q3, q4, q5, q6, q7, q8);
            const float mid = q4;

            const float sum = sum5[p];
            const float sq  = sq5[p];
            const float mean = sum * (1.0f / 25.0f);
            float var = (sq - sum * mean) * (1.0f / 24.0f);
            var = fmaxf(var, 0.0f);

            const float xc = center[p];
            const float rr = __builtin_amdgcn_rcpf(var + 1e-10f);
            float y = xc - noise_var * rr * (xc - mid + noise_bias);
            res[p] = fmaxf(y, 0.0f);
        }
        return res;
    };

    // ---- window A (rows oy0-2 .. oy0+2): insert row0 into shared sorted rows1..4 ----
    {
        float colA[8][5];
        #pragma unroll
        for (int k = 0; k < 8; ++k) {
            INSERT5(colA[k][0], colA[k][1], colA[k][2], colA[k][3], colA[k][4],
                    c[k][1], c[k][2], c[k][3], c[k][4], c[k][0]);
        }
        float4u resA = run_window(colA, centerA, sum5A, sq5A);
        *(float4u*)(outp + (size_t)oy0 * W + tile_x + tx * PX) = resA;
    }

    // ---- window B (rows oy0-1 .. oy0+3): insert row5 ----
    {
        float colB[8][5];
        #pragma unroll
        for (int k = 0; k < 8; ++k) {
            INSERT5(colB[k][0], colB[k][1], colB[k][2], colB[k][3], colB[k][4],
                    c[k][1], c[k][2], c[k][3], c[k][4], c[k][5]);
        }
        float4u resB = run_window(colB, centerB, sum5B, sq5B);
        *(float4u*)(outp + (size_t)(oy0 + 1) * W + tile_x + tx * PX) = resB;
    }
}

extern "C" void kernel_launch(void* const* d_in, const int* in_sizes, int n_in,
                              void* d_out, int out_size, void* d_ws, size_t ws_size,
                              hipStream_t stream)
{
    const float* x  = (const float*)d_in[0];
    const float* nv = (const float*)d_in[1];
    const float* nb = (const float*)d_in[2];
    float* out = (float*)d_out;

    const int H = 512, W = 512;
    const int B = in_sizes[0] / (H * W);   // 16 (C==1)

    dim3 block(BDX, BDY, 1);
    dim3 grid(W / TSX, H / TSY, B);
    denoise_median5_kernel<<<grid, block, 0, stream>>>(x, nv, nb, out, H, W);
}

// Round 5
// 31.635 us; speedup vs baseline: 1.2347x; 1.2347x over previous
//
#include <hip/hip_runtime.h>

#define PAD 2
#define PX 4                 // pixels per thread along x
#define BDX 16
#define BDY 16
#define TSX (BDX * PX)       // 64 outputs wide per block
#define TSY BDY              // 16 outputs high per block
#define LTW (TSX + 2 * PAD)  // 68 (= 17 float4 chunks)
#define LTH (TSY + 2 * PAD)  // 20
#define NCHUNK (LTH * LTW / 4)  // 340

// 16B vector with only 4B alignment guarantee (global loads at -2 offset)
typedef float float4u __attribute__((vector_size(16), aligned(4)));
typedef float v4f __attribute__((ext_vector_type(4)));

__device__ __forceinline__ float min3f(float a, float b, float c) {
    float r; asm("v_min3_f32 %0, %1, %2, %3" : "=v"(r) : "v"(a), "v"(b), "v"(c)); return r;
}
__device__ __forceinline__ float max3f(float a, float b, float c) {
    float r; asm("v_max3_f32 %0, %1, %2, %3" : "=v"(r) : "v"(a), "v"(b), "v"(c)); return r;
}
__device__ __forceinline__ float med3f(float a, float b, float c) {
    float r; asm("v_med3_f32 %0, %1, %2, %3" : "=v"(r) : "v"(a), "v"(b), "v"(c)); return r;
}

// compare-exchange (for MED9 network; dead halves are DCE'd)
#define CE(a, b) { float _lo = fminf(a, b), _hi = fmaxf(a, b); (a) = _lo; (b) = _hi; }

// median of 9 in q4 (Devillard 19-CE network; ~30 ops after DCE)
#define MED9(q0, q1, q2, q3, q4, q5, q6, q7, q8) \
    CE(q1, q2) CE(q4, q5) CE(q7, q8) \
    CE(q0, q1) CE(q3, q4) CE(q6, q7) \
    CE(q1, q2) CE(q4, q5) CE(q7, q8) \
    CE(q0, q3) CE(q5, q8) CE(q4, q7) \
    CE(q3, q6) CE(q1, q4) CE(q2, q5) \
    CE(q4, q7) CE(q4, q2) CE(q6, q4) \
    CE(q4, q2)

__global__ __launch_bounds__(256) void denoise_median5_kernel(
    const float* __restrict__ x,
    const float* __restrict__ noise_var_p,
    const float* __restrict__ noise_bias_p,
    float* __restrict__ out,
    int H, int W)
{
    __shared__ float tile[LTH][LTW];

    const float noise_var  = noise_var_p[0];
    const float noise_bias = noise_bias_p[0];

    const int b      = blockIdx.z;
    const int tile_y = blockIdx.y * TSY;
    const int tile_x = blockIdx.x * TSX;
    const int tx = threadIdx.x;
    const int ty = threadIdx.y;
    const int tid = ty * BDX + tx;

    const float* __restrict__ img = x + (size_t)b * H * W;

    const bool interior = (blockIdx.x > 0) && (blockIdx.x < gridDim.x - 1) &&
                          (blockIdx.y > 0) && (blockIdx.y < gridDim.y - 1);
    if (interior) {
        // Vectorized staging: 340 float4 chunks, linear chunk i -> tile[i/17][(i%17)*4].
        // Global source is 8B-aligned (tile_x-2): dwordx4 at dword alignment is legal.
        const float* gbase = img + (size_t)(tile_y - PAD) * W + (tile_x - PAD);
        {
            const int i = tid;                 // 0..255
            const int row = i / 17;
            const int cc  = i - row * 17;
            float4u v = *(const float4u*)(gbase + (size_t)row * W + cc * 4);
            *(float4u*)&tile[row][cc * 4] = v;   // 16B-aligned LDS write
        }
        if (tid < NCHUNK - 256) {              // 84 remaining chunks
            const int i = tid + 256;
            const int row = i / 17;
            const int cc  = i - row * 17;
            float4u v = *(const float4u*)(gbase + (size_t)row * W + cc * 4);
            *(float4u*)&tile[row][cc * 4] = v;
        }
    } else {
        // Edge blocks: scalar bounds-checked staging (zero pad).
        for (int i = tid; i < LTH * LTW; i += BDX * BDY) {
            const int ly = i / LTW;
            const int lx = i - ly * LTW;
            const int gy = tile_y + ly - PAD;
            const int gx = tile_x + lx - PAD;
            float v = 0.0f;
            if (gy >= 0 && gy < H && gx >= 0 && gx < W)
                v = img[(size_t)gy * W + gx];
            tile[ly][lx] = v;
        }
    }
    __syncthreads();

    // Load fragments as two float4 per row (cols tx*4 .. tx*4+7).
    v4f A[5], D[5];
    #pragma unroll
    for (int r = 0; r < 5; ++r) {
        A[r] = *(const v4f*)&tile[ty + r][tx * PX];
        D[r] = *(const v4f*)&tile[ty + r][tx * PX + 4];
    }

    // Column sums / sums of squares on packed vectors (v_pk_add/fma_f32).
    v4f SA = ((A[0] + A[1]) + (A[2] + A[3])) + A[4];
    v4f SD = ((D[0] + D[1]) + (D[2] + D[3])) + D[4];
    v4f QA = A[0] * A[0];
    v4f QD = D[0] * D[0];
    #pragma unroll
    for (int r = 1; r < 5; ++r) { QA = A[r] * A[r] + QA; QD = D[r] * D[r] + QD; }

    const float s8[8] = {SA.x, SA.y, SA.z, SA.w, SD.x, SD.y, SD.z, SD.w};
    const float q8[8] = {QA.x, QA.y, QA.z, QA.w, QD.x, QD.y, QD.z, QD.w};

    float sum5[PX], sq5[PX];
    sum5[0] = ((s8[0] + s8[1]) + (s8[2] + s8[3])) + s8[4];
    sq5[0]  = ((q8[0] + q8[1]) + (q8[2] + q8[3])) + q8[4];
    #pragma unroll
    for (int p = 1; p < PX; ++p) {
        sum5[p] = sum5[p - 1] - s8[p - 1] + s8[p + 4];
        sq5[p]  = sq5[p - 1]  - q8[p - 1] + q8[p + 4];
    }

    // Center pixels (raw values, col p+2 row 2).
    const float center[PX] = {A[2].z, A[2].w, D[2].x, D[2].y};

    // Unpack to 8 columns and sort each column (15-op network w/ min3/max3/med3).
    float c[8][5];
    #pragma unroll
    for (int r = 0; r < 5; ++r) {
        c[0][r] = A[r].x; c[1][r] = A[r].y; c[2][r] = A[r].z; c[3][r] = A[r].w;
        c[4][r] = D[r].x; c[5][r] = D[r].y; c[6][r] = D[r].z; c[7][r] = D[r].w;
    }
    #pragma unroll
    for (int k = 0; k < 8; ++k) {
        const float a1 = fminf(c[k][0], c[k][1]), a2 = fmaxf(c[k][0], c[k][1]);
        const float b1 = fminf(c[k][2], c[k][3]), b2 = fmaxf(c[k][2], c[k][3]);
        const float cc = c[k][4];
        const float t1 = fminf(a2, b2), t3 = fmaxf(a1, b1);
        const float M  = fmaxf(a2, b2), m  = fminf(a1, b1);
        c[k][0] = fminf(m, cc);                       // min of 5
        c[k][4] = fmaxf(M, cc);                       // max of 5
        c[k][2] = med3f(t1, t3, cc);                  // median of 5
        c[k][3] = max3f(t1, fminf(cc, M), t3);        // 2nd largest
        c[k][1] = min3f(t3, fmaxf(cc, m), t1);        // 2nd smallest
    }

    float4 res;
    float* resp = (float*)&res;

    #pragma unroll
    for (int p = 0; p < PX; ++p) {
        float A1, A2, B1, B2, B3, C1, C2, C3, D1, D2, D3, E1, E2;
        // row 0 (column minima): need sorted pos 3,4 (2nd-largest, largest)
        {
            const float a1 = fminf(c[p][0], c[p+1][0]), a2 = fmaxf(c[p][0], c[p+1][0]);
            const float b1 = fminf(c[p+2][0], c[p+3][0]), b2 = fmaxf(c[p+2][0], c[p+3][0]);
            const float cc = c[p+4][0];
            const float M = fmaxf(a2, b2), t1 = fminf(a2, b2), t3 = fmaxf(a1, b1);
            A2 = fmaxf(M, cc);
            A1 = max3f(t1, fminf(cc, M), t3);
        }
        // row 1: need pos 2,3,4 (median, 2nd-largest, largest)
        {
            const float a1 = fminf(c[p][1], c[p+1][1]), a2 = fmaxf(c[p][1], c[p+1][1]);
            const float b1 = fminf(c[p+2][1], c[p+3][1]), b2 = fmaxf(c[p+2][1], c[p+3][1]);
            const float cc = c[p+4][1];
            const float M = fmaxf(a2, b2), t1 = fminf(a2, b2), t3 = fmaxf(a1, b1);
            B3 = fmaxf(M, cc);
            B2 = max3f(t1, fminf(cc, M), t3);
            B1 = med3f(t1, t3, cc);
        }
        // row 2: need pos 1,2,3
        {
            const float a1 = fminf(c[p][2], c[p+1][2]), a2 = fmaxf(c[p][2], c[p+1][2]);
            const float b1 = fminf(c[p+2][2], c[p+3][2]), b2 = fmaxf(c[p+2][2], c[p+3][2]);
            const float cc = c[p+4][2];
            const float M = fmaxf(a2, b2), m = fminf(a1, b1);
            const float t1 = fminf(a2, b2), t3 = fmaxf(a1, b1);
            C2 = med3f(t1, t3, cc);
            C3 = max3f(t1, fminf(cc, M), t3);
            C1 = min3f(t3, fmaxf(cc, m), t1);
        }
        // row 3: need pos 0,1,2 (min, 2nd-smallest, median)
        {
            const float a1 = fminf(c[p][3], c[p+1][3]), a2 = fmaxf(c[p][3], c[p+1][3]);
            const float b1 = fminf(c[p+2][3], c[p+3][3]), b2 = fmaxf(c[p+2][3], c[p+3][3]);
            const float cc = c[p+4][3];
            const float m = fminf(a1, b1), t1 = fminf(a2, b2), t3 = fmaxf(a1, b1);
            D1 = fminf(m, cc);
            D2 = min3f(t3, fmaxf(cc, m), t1);
            D3 = med3f(t1, t3, cc);
        }
        // row 4 (column maxima): need pos 0,1 (min, 2nd-smallest)
        {
            const float a1 = fminf(c[p][4], c[p+1][4]), a2 = fmaxf(c[p][4], c[p+1][4]);
            const float b1 = fminf(c[p+2][4], c[p+3][4]), b2 = fmaxf(c[p+2][4], c[p+3][4]);
            const float cc = c[p+4][4];
            const float m = fminf(a1, b1), t1 = fminf(a2, b2), t3 = fmaxf(a1, b1);
            E1 = fminf(m, cc);
            E2 = min3f(t3, fmaxf(cc, m), t1);
        }

        // poset elimination: 13 candidates -> 9 (rank-counted, provably safe)
        const float mn1 = fminf(B3, D3);
        const float mn2 = fminf(C3, E2);
        const float mx1 = fmaxf(B1, D1);
        const float mx2 = fmaxf(A1, C1);

        float q0 = mx2, q1 = A2, q2 = B2, q3 = C2, q4 = D2,
              q5 = E1, q6 = mx1, q7 = mn1, q8 = mn2;
        MED9(q0, q1, q2, q3, q4, q5, q6, q7, q8);
        const float mid = q4;

        // unbiased variance from shared column sums
        const float sum = sum5[p];
        const float sq  = sq5[p];
        const float mean = sum * (1.0f / 25.0f);
        float var = (sq - sum * mean) * (1.0f / 24.0f);
        var = fmaxf(var, 0.0f);

        const float xc = center[p];
        const float rr = __builtin_amdgcn_rcpf(var + 1e-10f);
        float y = xc - noise_var * rr * (xc - mid + noise_bias);
        resp[p] = fmaxf(y, 0.0f);
    }

    const int gy = tile_y + ty;
    const int gx = tile_x + tx * PX;
    *(float4*)&out[((size_t)b * H + gy) * W + gx] = res;
}

extern "C" void kernel_launch(void* const* d_in, const int* in_sizes, int n_in,
                              void* d_out, int out_size, void* d_ws, size_t ws_size,
                              hipStream_t stream)
{
    const float* x  = (const float*)d_in[0];
    const float* nv = (const float*)d_in[1];
    const float* nb = (const float*)d_in[2];
    float* out = (float*)d_out;

    const int H = 512, W = 512;
    const int B = in_sizes[0] / (H * W);   // 16 (C==1)

    dim3 block(BDX, BDY, 1);
    dim3 grid(W / TSX, H / TSY, B);
    denoise_median5_kernel<<<grid, block, 0, stream>>>(x, nv, nb, out, H, W);
}